// Round 8
// baseline (200.685 us; speedup 1.0000x reference)
//
#include <hip/hip_runtime.h>

// Problem constants
#define B_   16
#define C_   512
#define HW_  4096
#define M_   1024   // pooled positions (HW/4)
#define TPAD 136    // LDS epilogue row pad (ushorts): 272 B = 16B-aligned rows

typedef __attribute__((ext_vector_type(8))) short bf16x8;   // 8 bf16 = 4 VGPR
typedef __attribute__((ext_vector_type(4))) float f32x4;

static __device__ __forceinline__ unsigned short f2bf(float f) {
    union { float f; unsigned u; } v; v.f = f;
    unsigned r = v.u + 0x7fffu + ((v.u >> 16) & 1u);  // RNE
    return (unsigned short)(r >> 16);
}
static __device__ __forceinline__ float bf2f(unsigned short h) {
    union { unsigned u; float f; } v; v.u = ((unsigned)h) << 16;
    return v.f;
}
static __device__ __forceinline__ void gload_lds16(const void* g, void* l) {
    __builtin_amdgcn_global_load_lds(
        (const __attribute__((address_space(1))) unsigned int*)g,
        (__attribute__((address_space(3))) unsigned int*)l, 16, 0, 0);
}

// ---------------------------------------------------------------------------
// K00: convert weights to bf16.
// Wb rows: [0,64) theta_w, [64,128) phi_w, [128,384) g_w. oWb = o_w [512][256].
__global__ __launch_bounds__(256) void k_weights(
    const float* __restrict__ thw, const float* __restrict__ phw,
    const float* __restrict__ gw,  const float* __restrict__ ow,
    unsigned short* __restrict__ Wb, unsigned short* __restrict__ oWb) {
    int i = blockIdx.x * 256 + threadIdx.x;
    if (i < 32768)        Wb[i] = f2bf(thw[i]);
    else if (i < 65536)   Wb[i] = f2bf(phw[i - 32768]);
    else if (i < 196608)  Wb[i] = f2bf(gw[i - 65536]);
    else if (i < 327680)  oWb[i - 196608] = f2bf(ow[i - 196608]);
}

// ---------------------------------------------------------------------------
// K0: x [B][512][4096] fp32 -> xT [B][4096][512] bf16 (LDS 64x64 transpose)
__global__ __launch_bounds__(256) void k_transpose_x(
    const float* __restrict__ x, unsigned short* __restrict__ xT) {
    __shared__ float tile[64][65];
    int b = blockIdx.z, c0 = blockIdx.y * 64, hw0 = blockIdx.x * 64;
    const float* xb = x + ((size_t)b * C_ + c0) * HW_ + hw0;
    int t = threadIdx.x;
    int r = t >> 4, c4 = (t & 15) * 4;
#pragma unroll
    for (int k = 0; k < 4; k++) {
        int row = r + k * 16;
        float4 v = *reinterpret_cast<const float4*>(xb + (size_t)row * HW_ + c4);
        tile[row][c4 + 0] = v.x; tile[row][c4 + 1] = v.y;
        tile[row][c4 + 2] = v.z; tile[row][c4 + 3] = v.w;
    }
    __syncthreads();
    unsigned short* o = xT + ((size_t)b * HW_ + hw0) * C_ + c0;
#pragma unroll
    for (int k = 0; k < 4; k++) {
        int hwr = r + k * 16;
        ushort4 u;
        u.x = f2bf(tile[c4 + 0][hwr]); u.y = f2bf(tile[c4 + 1][hwr]);
        u.z = f2bf(tile[c4 + 2][hwr]); u.w = f2bf(tile[c4 + 3][hwr]);
        *reinterpret_cast<ushort4*>(o + (size_t)hwr * C_ + c4) = u;
    }
}

// ---------------------------------------------------------------------------
// K1: projection GEMM per batch: P[384][4096] = Wb[384][512] @ xT_b^T.
// m97 structure (round-4 proven): 128x128 tile, BK=64, 4 waves (2x2), LDS-
// staged A/B via global_load_lds w16 with chunk-XOR swizzle pre-applied on the
// GLOBAL side. FUSED epilogue: theta -> theta_n transposed; phi/g -> 2x2
// maxpool -> phi_p / g_p. Each block covers 2 full H-rows.
__global__ __launch_bounds__(256, 4) void k_proj(
    const unsigned short* __restrict__ xT, const unsigned short* __restrict__ Wb,
    unsigned short* __restrict__ theta_n, unsigned short* __restrict__ phi_p,
    unsigned short* __restrict__ g_p) {
    __shared__ unsigned short smem[128 * TPAD];   // 34,816 B; aliases As|Bs
    unsigned short* As = smem;                    // ushort idx [0, 8192)
    unsigned short* Bs = smem + 8192;             // ushort idx [8192, 16384)

    int b = blockIdx.z, mt = blockIdx.y, bx = blockIdx.x;
    int hw0 = bx * 128;
    int tid = threadIdx.x, w = tid >> 6, lane = tid & 63;
    int l15 = lane & 15, q = lane >> 4;
    int wr = w >> 1, wc = w & 1;

    const unsigned short* Ab = Wb + (size_t)(mt * 128) * 512;
    const unsigned short* Bb = xT + ((size_t)b * HW_ + hw0) * 512;
    int trow = tid >> 3, tch = tid & 7;

    f32x4 acc[4][4] = {};
    for (int ks = 0; ks < 8; ks++) {
        int k0 = ks * 64;
        if (ks) __syncthreads();
#pragma unroll
        for (int i = 0; i < 4; i++) {
            int row = i * 32 + trow;
            int ch = tch ^ (row & 7);
            gload_lds16(Ab + (size_t)row * 512 + k0 + ch * 8, &As[(i * 256 + w * 64) * 8]);
        }
#pragma unroll
        for (int i = 0; i < 4; i++) {
            int row = i * 32 + trow;
            int ch = tch ^ (row & 7);
            gload_lds16(Bb + (size_t)row * 512 + k0 + ch * 8, &Bs[(i * 256 + w * 64) * 8]);
        }
        __syncthreads();
#pragma unroll
        for (int kk = 0; kk < 2; kk++) {
            bf16x8 af[4], bfr[4];
#pragma unroll
            for (int mi = 0; mi < 4; mi++) {
                int row = wr * 64 + mi * 16 + l15;
                int ch = (kk * 4 + q) ^ (row & 7);
                af[mi] = *(const bf16x8*)&As[row * 64 + ch * 8];
            }
#pragma unroll
            for (int ni = 0; ni < 4; ni++) {
                int row = wc * 64 + ni * 16 + l15;
                int ch = (kk * 4 + q) ^ (row & 7);
                bfr[ni] = *(const bf16x8*)&Bs[row * 64 + ch * 8];
            }
#pragma unroll
            for (int mi = 0; mi < 4; mi++)
#pragma unroll
                for (int ni = 0; ni < 4; ni++)
                    acc[mi][ni] = __builtin_amdgcn_mfma_f32_16x16x32_bf16(
                        af[mi], bfr[ni], acc[mi][ni], 0, 0, 0);
        }
    }

    // ---- epilogue: restage tile TRANSPOSED: smem[col(hw_l)][row(ch_l)], pad 136
    __syncthreads();
#pragma unroll
    for (int mi = 0; mi < 4; mi++)
#pragma unroll
        for (int ni = 0; ni < 4; ni++) {
            int col = wc * 64 + ni * 16 + l15;
            int row = wr * 64 + mi * 16 + q * 4;
            ushort4 u;
            u.x = f2bf(acc[mi][ni][0]); u.y = f2bf(acc[mi][ni][1]);
            u.z = f2bf(acc[mi][ni][2]); u.w = f2bf(acc[mi][ni][3]);
            *reinterpret_cast<ushort4*>(&smem[col * TPAD + row]) = u;
        }
    __syncthreads();

    if (mt == 0) {
        // theta rows 0..63 -> theta_n[b][hw][k]: thread t = 1 hw x 32 k, 64 B copy
        int hw_l = tid >> 1, kh = (tid & 1) * 32;
        const unsigned short* srcp = &smem[hw_l * TPAD + kh];
        unsigned short* dstp = theta_n + ((size_t)b * HW_ + hw0 + hw_l) * 64 + kh;
#pragma unroll
        for (int i = 0; i < 4; i++)
            *reinterpret_cast<uint4*>(dstp + i * 8) =
                *reinterpret_cast<const uint4*>(srcp + i * 8);
        // phi rows 64..127 -> pool -> phi_p[b][m][64]: thread = 8 m x 1 pc
        int pc = tid & 63, mg = tid >> 6;
#pragma unroll
        for (int j = 0; j < 8; j++) {
            int m_l = mg * 8 + j, w_ = m_l * 2;
            float v0 = bf2f(smem[(w_)      * TPAD + 64 + pc]);
            float v1 = bf2f(smem[(w_ + 1)  * TPAD + 64 + pc]);
            float v2 = bf2f(smem[(64 + w_) * TPAD + 64 + pc]);
            float v3 = bf2f(smem[(65 + w_) * TPAD + 64 + pc]);
            float v = fmaxf(fmaxf(v0, v1), fmaxf(v2, v3));
            phi_p[((size_t)b * M_ + bx * 32 + m_l) * 64 + pc] = f2bf(v);
        }
    } else {
        // g rows -> pool -> g_p[b][gc][1024]: thread = 1 gc x 16 m (32 B store)
        int lr = tid & 127, half = tid >> 7;
        int gc = (mt - 1) * 128 + lr;
        unsigned short* dst = g_p + ((size_t)b * 272 + gc) * M_ + bx * 32 + half * 16;
        unsigned short tmp[16];
#pragma unroll
        for (int i = 0; i < 16; i++) {
            int w_ = (half * 16 + i) * 2;
            float v0 = bf2f(smem[(w_)      * TPAD + lr]);
            float v1 = bf2f(smem[(w_ + 1)  * TPAD + lr]);
            float v2 = bf2f(smem[(64 + w_) * TPAD + lr]);
            float v3 = bf2f(smem[(65 + w_) * TPAD + lr]);
            tmp[i] = f2bf(fmaxf(fmaxf(v0, v1), fmaxf(v2, v3)));
        }
#pragma unroll
        for (int i = 0; i < 4; i++)
            *reinterpret_cast<ushort4*>(dst + i * 4) =
                *reinterpret_cast<const ushort4*>(&tmp[i * 4]);
    }
}

// ---------------------------------------------------------------------------
// K3: fused attention -> o_in [B][4096][256] bf16.
// Block = 512 threads (8 waves), 128 query rows (16/wave), batch b.
// T3 minimum-2-phase: KVBLK=32 m-chunks, phi+g double-buffered in LDS via
// global_load_lds w16 (chunk-XOR pre-swizzled on the GLOBAL side). Per chunk:
// issue STAGE(mc+1) -> compute chunk mc (S = theta@phi, P = exp(S), O += P@g^T)
// -> ONE barrier (compiler's vmcnt(0)-drain lands after full compute cover).
// Softmax denominator via a compile-time constant ones-fragment (g row 256
// equivalent), so only g rows 0..255 are ever staged.
__global__ __launch_bounds__(512, 4) void k_attn(
    const unsigned short* __restrict__ theta_n, const unsigned short* __restrict__ phi_p,
    const unsigned short* __restrict__ g_p, unsigned short* __restrict__ o_in) {
    __shared__ unsigned short g_s[2][256 * 32];    // 2 x 16 KB, row=c (64 B rows)
    __shared__ unsigned short phi_s[2][32 * 64];   // 2 x 4 KB,  row=m (128 B rows)
    __shared__ unsigned short p_lds[8][16][40];    // 10 KB, per-wave P tile [16n][32m]

    int b = blockIdx.y, n0 = blockIdx.x * 128;
    int tid = threadIdx.x, w = tid >> 6, lane = tid & 63;
    int l15 = lane & 15, q = lane >> 4;
    int nw = n0 + w * 16;

    // theta A-fragments (held all kernel): rows nw+l15, k = q*8 + [0..8) (+32)
    const unsigned short* th = theta_n + ((size_t)b * HW_ + nw + l15) * 64 + q * 8;
    bf16x8 a0 = *(const bf16x8*)(th);
    bf16x8 a1 = *(const bf16x8*)(th + 32);

    const unsigned short* phib = phi_p + (size_t)b * M_ * 64;
    const unsigned short* gb   = g_p   + (size_t)b * 272 * M_;

    // constant denominator B-fragment: row 256+l15 -> 1.0 iff l15==0, any k
    bf16x8 ones;
    {
        short v = (l15 == 0) ? (short)0x3F80 : (short)0;
#pragma unroll
        for (int i = 0; i < 8; i++) ones[i] = v;
    }

    // STAGE chunk mc_ into buffer bufi_:
    //  g: 1024 x 16B units; wave w covers units w*128 + i*64 + lane (i<2)
    //  phi: 256 x 16B units; waves 0..3 cover u = w*64 + lane
#define STAGE(mc_, bufi_)                                                      \
    {                                                                          \
        int m0_ = (mc_) * 32;                                                  \
        _Pragma("unroll")                                                      \
        for (int i = 0; i < 2; i++) {                                          \
            int u = w * 128 + i * 64 + lane;                                   \
            int row = u >> 2, ch = (u & 3) ^ (row & 3);                        \
            gload_lds16(gb + (size_t)row * M_ + m0_ + ch * 8,                  \
                        &g_s[bufi_][(w * 128 + i * 64) * 8]);                  \
        }                                                                      \
        if (w < 4) {                                                           \
            int u = w * 64 + lane;                                             \
            int row = u >> 3, ch = (u & 7) ^ (row & 7);                        \
            gload_lds16(phib + (size_t)(m0_ + row) * 64 + ch * 8,              \
                        &phi_s[bufi_][w * 512]);                               \
        }                                                                      \
    }

    f32x4 acc[17] = {};  // 16 c-frags (c 0..255) + frag 16 = denominator column
    STAGE(0, 0);
    __syncthreads();     // drain prologue stage
    int sw = l15 & 7;
    for (int mc = 0; mc < 32; mc++) {
        int cur = mc & 1;
        // ---- issue next chunk's stage (covered by this chunk's compute)
        if (mc < 31) STAGE(mc + 1, cur ^ 1);
        // ---- S phase: S[16n][32m] in 2 fragments, exp -> bf16 -> per-wave LDS
#pragma unroll
        for (int f = 0; f < 2; f++) {
            const unsigned short* pr = &phi_s[cur][(f * 16 + l15) * 64];
            bf16x8 b0 = *(const bf16x8*)(pr + (q ^ sw) * 8);
            bf16x8 b1 = *(const bf16x8*)(pr + ((q + 4) ^ sw) * 8);
            f32x4 s = {};
            s = __builtin_amdgcn_mfma_f32_16x16x32_bf16(a0, b0, s, 0, 0, 0);
            s = __builtin_amdgcn_mfma_f32_16x16x32_bf16(a1, b1, s, 0, 0, 0);
#pragma unroll
            for (int j = 0; j < 4; j++)
                p_lds[w][q * 4 + j][f * 16 + l15] = f2bf(__expf(s[j]));
        }
        // ---- P A-fragment from LDS (same-wave dep; compiler inserts lgkmcnt)
        bf16x8 p0 = *(const bf16x8*)&p_lds[w][l15][q * 8];
        // ---- O phase: acc[cf] += P[16n][32m] @ g^T[32m][16c]
#pragma unroll
        for (int cf = 0; cf < 16; cf++) {
            int grow = cf * 16 + l15;
            bf16x8 g0 = *(const bf16x8*)&g_s[cur][grow * 32 + ((q ^ (grow & 3)) * 8)];
            acc[cf] = __builtin_amdgcn_mfma_f32_16x16x32_bf16(p0, g0, acc[cf], 0, 0, 0);
        }
        acc[16] = __builtin_amdgcn_mfma_f32_16x16x32_bf16(p0, ones, acc[16], 0, 0, 0);
        // ---- one barrier per chunk: drains next-chunk stage (full compute cover)
        __syncthreads();
    }
#undef STAGE

    // ---- epilogue: divide by denominator (frag 16, col 0 => lanes l15==0)
    float dinv[4];
#pragma unroll
    for (int j = 0; j < 4; j++) {
        float d = __shfl(acc[16][j], (lane & 48), 64);
        dinv[j] = 1.0f / d;
    }
#pragma unroll
    for (int cf = 0; cf < 16; cf++)
#pragma unroll
        for (int j = 0; j < 4; j++)
            o_in[((size_t)b * HW_ + nw + q * 4 + j) * 256 + cf * 16 + l15] =
                f2bf(acc[cf][j] * dinv[j]);
}

// ---------------------------------------------------------------------------
// K4: output projection + residual: out[b][cout][hw] = gamma * (o_in @ oW^T) + x
// m97 mainloop + LDS-restaged epilogue: tile -> smem[row][col] (pad 136),
// then 32-lane groups write 512 B contiguous float4 rows (x reads coalesced).
__global__ __launch_bounds__(256, 4) void k_oproj(
    const unsigned short* __restrict__ o_in, const unsigned short* __restrict__ oWb,
    const float* __restrict__ x, const float* __restrict__ gamma_p,
    float* __restrict__ out) {
    __shared__ unsigned short smem[128 * TPAD];   // 34,816 B; aliases As|Bs
    unsigned short* As = smem;
    unsigned short* Bs = smem + 8192;

    int b = blockIdx.z, mt = blockIdx.y, hw0 = blockIdx.x * 128;
    int tid = threadIdx.x, w = tid >> 6, lane = tid & 63;
    int l15 = lane & 15, q = lane >> 4;
    int wr = w >> 1, wc = w & 1;

    const unsigned short* Ab = oWb + (size_t)(mt * 128) * 256;
    const unsigned short* Bb = o_in + ((size_t)b * HW_ + hw0) * 256;
    int trow = tid >> 3, tch = tid & 7;

    f32x4 acc[4][4] = {};
    for (int ks = 0; ks < 4; ks++) {
        int k0 = ks * 64;
        if (ks) __syncthreads();
#pragma unroll
        for (int i = 0; i < 4; i++) {
            int row = i * 32 + trow;
            int ch = tch ^ (row & 7);
            gload_lds16(Ab + (size_t)row * 256 + k0 + ch * 8, &As[(i * 256 + w * 64) * 8]);
        }
#pragma unroll
        for (int i = 0; i < 4; i++) {
            int row = i * 32 + trow;
            int ch = tch ^ (row & 7);
            gload_lds16(Bb + (size_t)row * 256 + k0 + ch * 8, &Bs[(i * 256 + w * 64) * 8]);
        }
        __syncthreads();
#pragma unroll
        for (int kk = 0; kk < 2; kk++) {
            bf16x8 af[4], bfr[4];
#pragma unroll
            for (int mi = 0; mi < 4; mi++) {
                int row = wr * 64 + mi * 16 + l15;
                int ch = (kk * 4 + q) ^ (row & 7);
                af[mi] = *(const bf16x8*)&As[row * 64 + ch * 8];
            }
#pragma unroll
            for (int ni = 0; ni < 4; ni++) {
                int row = wc * 64 + ni * 16 + l15;
                int ch = (kk * 4 + q) ^ (row & 7);
                bfr[ni] = *(const bf16x8*)&Bs[row * 64 + ch * 8];
            }
#pragma unroll
            for (int mi = 0; mi < 4; mi++)
#pragma unroll
                for (int ni = 0; ni < 4; ni++)
                    acc[mi][ni] = __builtin_amdgcn_mfma_f32_16x16x32_bf16(
                        af[mi], bfr[ni], acc[mi][ni], 0, 0, 0);
        }
    }

    // ---- epilogue: restage row-major smem[row(cout_l)][col(hw_l)], pad 136
    __syncthreads();
#pragma unroll
    for (int mi = 0; mi < 4; mi++)
#pragma unroll
        for (int ni = 0; ni < 4; ni++) {
            int col = wc * 64 + ni * 16 + l15;
            int rb = wr * 64 + mi * 16 + q * 4;
#pragma unroll
            for (int j = 0; j < 4; j++)
                smem[(rb + j) * TPAD + col] = f2bf(acc[mi][ni][j]);
        }
    __syncthreads();

    float gam = *gamma_p;
    int sub = tid >> 5, p32 = tid & 31;
#pragma unroll
    for (int p = 0; p < 16; p++) {
        int row = p * 8 + sub;
        ushort4 v = *reinterpret_cast<const ushort4*>(&smem[row * TPAD + p32 * 4]);
        size_t idx = ((size_t)b * C_ + mt * 128 + row) * HW_ + hw0 + p32 * 4;
        float4 xv = *reinterpret_cast<const float4*>(x + idx);
        float4 o;
        o.x = gam * bf2f(v.x) + xv.x;
        o.y = gam * bf2f(v.y) + xv.y;
        o.z = gam * bf2f(v.z) + xv.z;
        o.w = gam * bf2f(v.w) + xv.w;
        *reinterpret_cast<float4*>(out + idx) = o;
    }
}

// ---------------------------------------------------------------------------
extern "C" void kernel_launch(void* const* d_in, const int* in_sizes, int n_in,
                              void* d_out, int out_size, void* d_ws, size_t ws_size,
                              hipStream_t stream) {
    const float* x     = (const float*)d_in[0];
    const float* thw   = (const float*)d_in[1];
    const float* phw   = (const float*)d_in[2];
    const float* gw    = (const float*)d_in[3];
    const float* ow    = (const float*)d_in[4];
    const float* gamma = (const float*)d_in[5];
    float* out = (float*)d_out;

    char* ws = (char*)d_ws;
    // workspace layout (bytes), all 256-aligned; total 120,717,312
    unsigned short* xT   = (unsigned short*)(ws + 0);          //  67,108,864
    unsigned short* Wb   = (unsigned short*)(ws + 67108864);   //     393,216
    unsigned short* oWb  = (unsigned short*)(ws + 67502080);   //     262,144
    unsigned short* oin  = (unsigned short*)(ws + 67764224);   //  33,554,432
    unsigned short* thn  = (unsigned short*)(ws + 101318656);  //   8,388,608
    unsigned short* phip = (unsigned short*)(ws + 109707264);  //   2,097,152
    unsigned short* gp   = (unsigned short*)(ws + 111804416);  //   8,912,896

    hipLaunchKernelGGL(k_weights, dim3(1280), dim3(256), 0, stream, thw, phw, gw, ow, Wb, oWb);
    hipLaunchKernelGGL(k_transpose_x, dim3(64, 8, 16), dim3(256), 0, stream, x, xT);
    hipLaunchKernelGGL(k_proj, dim3(32, 3, 16), dim3(256), 0, stream, xT, Wb, thn, phip, gp);
    hipLaunchKernelGGL(k_attn, dim3(32, 16), dim3(512), 0, stream, thn, phip, gp, oin);
    hipLaunchKernelGGL(k_oproj, dim3(32, 4, 16), dim3(256), 0, stream, oin, oWb, x, gamma, out);
}

// Round 9
// 192.263 us; speedup vs baseline: 1.0438x; 1.0438x over previous
//
#include <hip/hip_runtime.h>

// Problem constants
#define B_   16
#define C_   512
#define HW_  4096
#define M_   1024   // pooled positions (HW/4)
#define TPAD 136    // LDS epilogue row pad (ushorts): 272 B = 16B-aligned rows

typedef __attribute__((ext_vector_type(8))) short bf16x8;   // 8 bf16 = 4 VGPR
typedef __attribute__((ext_vector_type(4))) float f32x4;

static __device__ __forceinline__ unsigned short f2bf(float f) {
    union { float f; unsigned u; } v; v.f = f;
    unsigned r = v.u + 0x7fffu + ((v.u >> 16) & 1u);  // RNE
    return (unsigned short)(r >> 16);
}
static __device__ __forceinline__ float bf2f(unsigned short h) {
    union { unsigned u; float f; } v; v.u = ((unsigned)h) << 16;
    return v.f;
}
static __device__ __forceinline__ void gload_lds16(const void* g, void* l) {
    __builtin_amdgcn_global_load_lds(
        (const __attribute__((address_space(1))) unsigned int*)g,
        (__attribute__((address_space(3))) unsigned int*)l, 16, 0, 0);
}

// ---------------------------------------------------------------------------
// K00: convert weights to bf16.
// Wb rows: [0,64) theta_w, [64,128) phi_w, [128,384) g_w. oWb = o_w [512][256].
__global__ __launch_bounds__(256) void k_weights(
    const float* __restrict__ thw, const float* __restrict__ phw,
    const float* __restrict__ gw,  const float* __restrict__ ow,
    unsigned short* __restrict__ Wb, unsigned short* __restrict__ oWb) {
    int i = blockIdx.x * 256 + threadIdx.x;
    if (i < 32768)        Wb[i] = f2bf(thw[i]);
    else if (i < 65536)   Wb[i] = f2bf(phw[i - 32768]);
    else if (i < 196608)  Wb[i] = f2bf(gw[i - 65536]);
    else if (i < 327680)  oWb[i - 196608] = f2bf(ow[i - 196608]);
}

// ---------------------------------------------------------------------------
// K0: x [B][512][4096] fp32 -> xT [B][4096][512] bf16 (LDS 64x64 transpose)
__global__ __launch_bounds__(256) void k_transpose_x(
    const float* __restrict__ x, unsigned short* __restrict__ xT) {
    __shared__ float tile[64][65];
    int b = blockIdx.z, c0 = blockIdx.y * 64, hw0 = blockIdx.x * 64;
    const float* xb = x + ((size_t)b * C_ + c0) * HW_ + hw0;
    int t = threadIdx.x;
    int r = t >> 4, c4 = (t & 15) * 4;
#pragma unroll
    for (int k = 0; k < 4; k++) {
        int row = r + k * 16;
        float4 v = *reinterpret_cast<const float4*>(xb + (size_t)row * HW_ + c4);
        tile[row][c4 + 0] = v.x; tile[row][c4 + 1] = v.y;
        tile[row][c4 + 2] = v.z; tile[row][c4 + 3] = v.w;
    }
    __syncthreads();
    unsigned short* o = xT + ((size_t)b * HW_ + hw0) * C_ + c0;
#pragma unroll
    for (int k = 0; k < 4; k++) {
        int hwr = r + k * 16;
        ushort4 u;
        u.x = f2bf(tile[c4 + 0][hwr]); u.y = f2bf(tile[c4 + 1][hwr]);
        u.z = f2bf(tile[c4 + 2][hwr]); u.w = f2bf(tile[c4 + 3][hwr]);
        *reinterpret_cast<ushort4*>(o + (size_t)hwr * C_ + c4) = u;
    }
}

// ---------------------------------------------------------------------------
// K1: projection GEMM per batch: P[384][4096] = Wb[384][512] @ xT_b^T.
// m97 structure (round-4 proven): 128x128 tile, BK=64, 4 waves (2x2), LDS-
// staged A/B via global_load_lds w16 with chunk-XOR swizzle pre-applied on the
// GLOBAL side. FUSED epilogue: theta -> theta_n transposed; phi/g -> 2x2
// maxpool -> phi_p / g_p. Each block covers 2 full H-rows.
__global__ __launch_bounds__(256, 4) void k_proj(
    const unsigned short* __restrict__ xT, const unsigned short* __restrict__ Wb,
    unsigned short* __restrict__ theta_n, unsigned short* __restrict__ phi_p,
    unsigned short* __restrict__ g_p) {
    __shared__ unsigned short smem[128 * TPAD];   // 34,816 B; aliases As|Bs
    unsigned short* As = smem;                    // ushort idx [0, 8192)
    unsigned short* Bs = smem + 8192;             // ushort idx [8192, 16384)

    int b = blockIdx.z, mt = blockIdx.y, bx = blockIdx.x;
    int hw0 = bx * 128;
    int tid = threadIdx.x, w = tid >> 6, lane = tid & 63;
    int l15 = lane & 15, q = lane >> 4;
    int wr = w >> 1, wc = w & 1;

    const unsigned short* Ab = Wb + (size_t)(mt * 128) * 512;
    const unsigned short* Bb = xT + ((size_t)b * HW_ + hw0) * 512;
    int trow = tid >> 3, tch = tid & 7;

    f32x4 acc[4][4] = {};
    for (int ks = 0; ks < 8; ks++) {
        int k0 = ks * 64;
        if (ks) __syncthreads();
#pragma unroll
        for (int i = 0; i < 4; i++) {
            int row = i * 32 + trow;
            int ch = tch ^ (row & 7);
            gload_lds16(Ab + (size_t)row * 512 + k0 + ch * 8, &As[(i * 256 + w * 64) * 8]);
        }
#pragma unroll
        for (int i = 0; i < 4; i++) {
            int row = i * 32 + trow;
            int ch = tch ^ (row & 7);
            gload_lds16(Bb + (size_t)row * 512 + k0 + ch * 8, &Bs[(i * 256 + w * 64) * 8]);
        }
        __syncthreads();
#pragma unroll
        for (int kk = 0; kk < 2; kk++) {
            bf16x8 af[4], bfr[4];
#pragma unroll
            for (int mi = 0; mi < 4; mi++) {
                int row = wr * 64 + mi * 16 + l15;
                int ch = (kk * 4 + q) ^ (row & 7);
                af[mi] = *(const bf16x8*)&As[row * 64 + ch * 8];
            }
#pragma unroll
            for (int ni = 0; ni < 4; ni++) {
                int row = wc * 64 + ni * 16 + l15;
                int ch = (kk * 4 + q) ^ (row & 7);
                bfr[ni] = *(const bf16x8*)&Bs[row * 64 + ch * 8];
            }
#pragma unroll
            for (int mi = 0; mi < 4; mi++)
#pragma unroll
                for (int ni = 0; ni < 4; ni++)
                    acc[mi][ni] = __builtin_amdgcn_mfma_f32_16x16x32_bf16(
                        af[mi], bfr[ni], acc[mi][ni], 0, 0, 0);
        }
    }

    // ---- epilogue: restage tile TRANSPOSED: smem[col(hw_l)][row(ch_l)], pad 136
    __syncthreads();
#pragma unroll
    for (int mi = 0; mi < 4; mi++)
#pragma unroll
        for (int ni = 0; ni < 4; ni++) {
            int col = wc * 64 + ni * 16 + l15;
            int row = wr * 64 + mi * 16 + q * 4;
            ushort4 u;
            u.x = f2bf(acc[mi][ni][0]); u.y = f2bf(acc[mi][ni][1]);
            u.z = f2bf(acc[mi][ni][2]); u.w = f2bf(acc[mi][ni][3]);
            *reinterpret_cast<ushort4*>(&smem[col * TPAD + row]) = u;
        }
    __syncthreads();

    if (mt == 0) {
        // theta rows 0..63 -> theta_n[b][hw][k]: thread t = 1 hw x 32 k, 64 B copy
        int hw_l = tid >> 1, kh = (tid & 1) * 32;
        const unsigned short* srcp = &smem[hw_l * TPAD + kh];
        unsigned short* dstp = theta_n + ((size_t)b * HW_ + hw0 + hw_l) * 64 + kh;
#pragma unroll
        for (int i = 0; i < 4; i++)
            *reinterpret_cast<uint4*>(dstp + i * 8) =
                *reinterpret_cast<const uint4*>(srcp + i * 8);
        // phi rows 64..127 -> pool -> phi_p[b][m][64]: thread = 8 m x 1 pc
        int pc = tid & 63, mg = tid >> 6;
#pragma unroll
        for (int j = 0; j < 8; j++) {
            int m_l = mg * 8 + j, w_ = m_l * 2;
            float v0 = bf2f(smem[(w_)      * TPAD + 64 + pc]);
            float v1 = bf2f(smem[(w_ + 1)  * TPAD + 64 + pc]);
            float v2 = bf2f(smem[(64 + w_) * TPAD + 64 + pc]);
            float v3 = bf2f(smem[(65 + w_) * TPAD + 64 + pc]);
            float v = fmaxf(fmaxf(v0, v1), fmaxf(v2, v3));
            phi_p[((size_t)b * M_ + bx * 32 + m_l) * 64 + pc] = f2bf(v);
        }
    } else {
        // g rows -> pool -> g_p[b][gc][1024]: thread = 1 gc x 16 m (32 B store)
        int lr = tid & 127, half = tid >> 7;
        int gc = (mt - 1) * 128 + lr;
        unsigned short* dst = g_p + ((size_t)b * 256 + gc) * M_ + bx * 32 + half * 16;
        unsigned short tmp[16];
#pragma unroll
        for (int i = 0; i < 16; i++) {
            int w_ = (half * 16 + i) * 2;
            float v0 = bf2f(smem[(w_)      * TPAD + lr]);
            float v1 = bf2f(smem[(w_ + 1)  * TPAD + lr]);
            float v2 = bf2f(smem[(64 + w_) * TPAD + lr]);
            float v3 = bf2f(smem[(65 + w_) * TPAD + lr]);
            tmp[i] = f2bf(fmaxf(fmaxf(v0, v1), fmaxf(v2, v3)));
        }
#pragma unroll
        for (int i = 0; i < 4; i++)
            *reinterpret_cast<ushort4*>(dst + i * 4) =
                *reinterpret_cast<const ushort4*>(&tmp[i * 4]);
    }
}

// ---------------------------------------------------------------------------
// K3: fused attention -> o_in [B][4096][256] bf16.
// Block = 256 threads (4 waves), 32 query rows PER WAVE (128/block), batch b.
// Rationale (r8 post-mortem): attn is LDS-port-bound; doubling rows/wave makes
// each g-fragment read feed 2 MFMA (was 1) and halves LDS bytes/CU.
// Per m-chunk (64 cols): stage phi[64][64] + g[256][64] via global_load_lds
// w16 (chunk-XOR pre-swizzled on the GLOBAL side), then S = theta@phi,
// P = exp(S) (no max-sub; logits bounded), O += P@g^T. Softmax denominator
// via compile-time ones-fragment (acc[t][16]); g rows 256+ never exist.
__global__ __launch_bounds__(256, 2) void k_attn(
    const unsigned short* __restrict__ theta_n, const unsigned short* __restrict__ phi_p,
    const unsigned short* __restrict__ g_p, unsigned short* __restrict__ o_in) {
    __shared__ unsigned short phi_s[64 * 64];      //  8 KB, row=m (64 elems, 8 chunks)
    __shared__ unsigned short g_s[256 * 64];       // 32 KB, row=c
    __shared__ unsigned short p_lds[4][32][68];    // 17 KB, per-wave P [32n][64m], pad 68

    int b = blockIdx.y, n0 = blockIdx.x * 128;
    int tid = threadIdx.x, w = tid >> 6, lane = tid & 63;
    int l15 = lane & 15, q = lane >> 4;
    int nw = n0 + w * 32;

    // theta A-fragments (held all kernel): 2 row-groups x 2 k-frags
    const unsigned short* th = theta_n + ((size_t)b * HW_ + nw + l15) * 64 + q * 8;
    bf16x8 a[2][2];
    a[0][0] = *(const bf16x8*)(th);            a[0][1] = *(const bf16x8*)(th + 32);
    a[1][0] = *(const bf16x8*)(th + 16 * 64);  a[1][1] = *(const bf16x8*)(th + 16 * 64 + 32);

    const unsigned short* phib = phi_p + (size_t)b * M_ * 64;
    const unsigned short* gb   = g_p   + (size_t)b * 256 * M_;

    // constant denominator B-fragment: column n=l15 -> 1.0 iff l15==0, all k
    bf16x8 ones;
    {
        short v = (l15 == 0) ? (short)0x3F80 : (short)0;
#pragma unroll
        for (int i = 0; i < 8; i++) ones[i] = v;
    }

    int sw = l15 & 7;  // read-side XOR (row & 7 == l15 & 7 for fragment rows)

    f32x4 acc[2][17] = {};  // [row-group][16 c-frags + denom]
    for (int mc = 0; mc < 16; mc++) {
        int m0 = mc * 64;
        __syncthreads();   // prior chunk's LDS reads complete before overwrite
        // ---- stage phi chunk: 512 x 16B units, 2 issues/thread
#pragma unroll
        for (int i = 0; i < 2; i++) {
            int u = i * 256 + tid;
            int row = u >> 3, ch = (lane & 7) ^ (row & 7);
            gload_lds16(phib + (size_t)(m0 + row) * 64 + ch * 8,
                        &phi_s[(i * 256 + w * 64) * 8]);
        }
        // ---- stage g chunk: 2048 x 16B units, 8 issues/thread
#pragma unroll
        for (int i = 0; i < 8; i++) {
            int u = i * 256 + tid;
            int row = u >> 3, ch = (lane & 7) ^ (row & 7);
            gload_lds16(gb + (size_t)row * M_ + m0 + ch * 8,
                        &g_s[(i * 256 + w * 64) * 8]);
        }
        __syncthreads();   // vmcnt(0) drain + barrier

        // ---- S phase: S[32n][64m]; phi reads amortize over 2 row-groups
#pragma unroll
        for (int f = 0; f < 4; f++) {
            const unsigned short* pr = &phi_s[(f * 16 + l15) * 64];
            bf16x8 b0 = *(const bf16x8*)(pr + (q ^ sw) * 8);
            bf16x8 b1 = *(const bf16x8*)(pr + ((q + 4) ^ sw) * 8);
#pragma unroll
            for (int t = 0; t < 2; t++) {
                f32x4 s = {};
                s = __builtin_amdgcn_mfma_f32_16x16x32_bf16(a[t][0], b0, s, 0, 0, 0);
                s = __builtin_amdgcn_mfma_f32_16x16x32_bf16(a[t][1], b1, s, 0, 0, 0);
#pragma unroll
                for (int j = 0; j < 4; j++)
                    p_lds[w][t * 16 + q * 4 + j][f * 16 + l15] = f2bf(__expf(s[j]));
            }
        }
        // ---- P A-fragments from LDS (same-wave dep; compiler inserts lgkmcnt)
        bf16x8 p[2][2];
#pragma unroll
        for (int t = 0; t < 2; t++) {
            p[t][0] = *(const bf16x8*)&p_lds[w][t * 16 + l15][q * 8];
            p[t][1] = *(const bf16x8*)&p_lds[w][t * 16 + l15][32 + q * 8];
        }
        // ---- O phase: each g-fragment read feeds BOTH row-groups (2x amortize)
#pragma unroll
        for (int cf = 0; cf < 16; cf++) {
            const unsigned short* gr = &g_s[(cf * 16 + l15) * 64];
            bf16x8 g0 = *(const bf16x8*)(gr + (q ^ sw) * 8);
            bf16x8 g1 = *(const bf16x8*)(gr + ((q + 4) ^ sw) * 8);
#pragma unroll
            for (int t = 0; t < 2; t++) {
                acc[t][cf] = __builtin_amdgcn_mfma_f32_16x16x32_bf16(p[t][0], g0, acc[t][cf], 0, 0, 0);
                acc[t][cf] = __builtin_amdgcn_mfma_f32_16x16x32_bf16(p[t][1], g1, acc[t][cf], 0, 0, 0);
            }
        }
#pragma unroll
        for (int t = 0; t < 2; t++) {
            acc[t][16] = __builtin_amdgcn_mfma_f32_16x16x32_bf16(p[t][0], ones, acc[t][16], 0, 0, 0);
            acc[t][16] = __builtin_amdgcn_mfma_f32_16x16x32_bf16(p[t][1], ones, acc[t][16], 0, 0, 0);
        }
    }

    // ---- epilogue: divide by denominator (frag 16, col 0 => lanes l15==0)
#pragma unroll
    for (int t = 0; t < 2; t++) {
        float dinv[4];
#pragma unroll
        for (int j = 0; j < 4; j++) {
            float d = __shfl(acc[t][16][j], (lane & 48), 64);
            dinv[j] = 1.0f / d;
        }
#pragma unroll
        for (int cf = 0; cf < 16; cf++)
#pragma unroll
            for (int j = 0; j < 4; j++)
                o_in[((size_t)b * HW_ + nw + t * 16 + q * 4 + j) * 256 + cf * 16 + l15] =
                    f2bf(acc[t][cf][j] * dinv[j]);
    }
}

// ---------------------------------------------------------------------------
// K4: output projection + residual: out[b][cout][hw] = gamma * (o_in @ oW^T) + x
// m97 mainloop + LDS-restaged epilogue: tile -> smem[row][col] (pad 136),
// then 32-lane groups write 512 B contiguous float4 rows (x reads coalesced).
__global__ __launch_bounds__(256, 4) void k_oproj(
    const unsigned short* __restrict__ o_in, const unsigned short* __restrict__ oWb,
    const float* __restrict__ x, const float* __restrict__ gamma_p,
    float* __restrict__ out) {
    __shared__ unsigned short smem[128 * TPAD];   // 34,816 B; aliases As|Bs
    unsigned short* As = smem;
    unsigned short* Bs = smem + 8192;

    int b = blockIdx.z, mt = blockIdx.y, hw0 = blockIdx.x * 128;
    int tid = threadIdx.x, w = tid >> 6, lane = tid & 63;
    int l15 = lane & 15, q = lane >> 4;
    int wr = w >> 1, wc = w & 1;

    const unsigned short* Ab = oWb + (size_t)(mt * 128) * 256;
    const unsigned short* Bb = o_in + ((size_t)b * HW_ + hw0) * 256;
    int trow = tid >> 3, tch = tid & 7;

    f32x4 acc[4][4] = {};
    for (int ks = 0; ks < 4; ks++) {
        int k0 = ks * 64;
        if (ks) __syncthreads();
#pragma unroll
        for (int i = 0; i < 4; i++) {
            int row = i * 32 + trow;
            int ch = tch ^ (row & 7);
            gload_lds16(Ab + (size_t)row * 256 + k0 + ch * 8, &As[(i * 256 + w * 64) * 8]);
        }
#pragma unroll
        for (int i = 0; i < 4; i++) {
            int row = i * 32 + trow;
            int ch = tch ^ (row & 7);
            gload_lds16(Bb + (size_t)row * 256 + k0 + ch * 8, &Bs[(i * 256 + w * 64) * 8]);
        }
        __syncthreads();
#pragma unroll
        for (int kk = 0; kk < 2; kk++) {
            bf16x8 af[4], bfr[4];
#pragma unroll
            for (int mi = 0; mi < 4; mi++) {
                int row = wr * 64 + mi * 16 + l15;
                int ch = (kk * 4 + q) ^ (row & 7);
                af[mi] = *(const bf16x8*)&As[row * 64 + ch * 8];
            }
#pragma unroll
            for (int ni = 0; ni < 4; ni++) {
                int row = wc * 64 + ni * 16 + l15;
                int ch = (kk * 4 + q) ^ (row & 7);
                bfr[ni] = *(const bf16x8*)&Bs[row * 64 + ch * 8];
            }
#pragma unroll
            for (int mi = 0; mi < 4; mi++)
#pragma unroll
                for (int ni = 0; ni < 4; ni++)
                    acc[mi][ni] = __builtin_amdgcn_mfma_f32_16x16x32_bf16(
                        af[mi], bfr[ni], acc[mi][ni], 0, 0, 0);
        }
    }

    // ---- epilogue: restage row-major smem[row(cout_l)][col(hw_l)], pad 136
    __syncthreads();
#pragma unroll
    for (int mi = 0; mi < 4; mi++)
#pragma unroll
        for (int ni = 0; ni < 4; ni++) {
            int col = wc * 64 + ni * 16 + l15;
            int rb = wr * 64 + mi * 16 + q * 4;
#pragma unroll
            for (int j = 0; j < 4; j++)
                smem[(rb + j) * TPAD + col] = f2bf(acc[mi][ni][j]);
        }
    __syncthreads();

    float gam = *gamma_p;
    int sub = tid >> 5, p32 = tid & 31;
#pragma unroll
    for (int p = 0; p < 16; p++) {
        int row = p * 8 + sub;
        ushort4 v = *reinterpret_cast<const ushort4*>(&smem[row * TPAD + p32 * 4]);
        size_t idx = ((size_t)b * C_ + mt * 128 + row) * HW_ + hw0 + p32 * 4;
        float4 xv = *reinterpret_cast<const float4*>(x + idx);
        float4 o;
        o.x = gam * bf2f(v.x) + xv.x;
        o.y = gam * bf2f(v.y) + xv.y;
        o.z = gam * bf2f(v.z) + xv.z;
        o.w = gam * bf2f(v.w) + xv.w;
        *reinterpret_cast<float4*>(out + idx) = o;
    }
}

// ---------------------------------------------------------------------------
extern "C" void kernel_launch(void* const* d_in, const int* in_sizes, int n_in,
                              void* d_out, int out_size, void* d_ws, size_t ws_size,
                              hipStream_t stream) {
    const float* x     = (const float*)d_in[0];
    const float* thw   = (const float*)d_in[1];
    const float* phw   = (const float*)d_in[2];
    const float* gw    = (const float*)d_in[3];
    const float* ow    = (const float*)d_in[4];
    const float* gamma = (const float*)d_in[5];
    float* out = (float*)d_out;

    char* ws = (char*)d_ws;
    // workspace layout (bytes), all 256-aligned
    unsigned short* xT   = (unsigned short*)(ws + 0);          //  67,108,864
    unsigned short* Wb   = (unsigned short*)(ws + 67108864);   //     393,216
    unsigned short* oWb  = (unsigned short*)(ws + 67502080);   //     262,144
    unsigned short* oin  = (unsigned short*)(ws + 67764224);   //  33,554,432
    unsigned short* thn  = (unsigned short*)(ws + 101318656);  //   8,388,608
    unsigned short* phip = (unsigned short*)(ws + 109707264);  //   2,097,152
    unsigned short* gp   = (unsigned short*)(ws + 111804416);  //   8,388,608 (256 rows/b)

    hipLaunchKernelGGL(k_weights, dim3(1280), dim3(256), 0, stream, thw, phw, gw, ow, Wb, oWb);
    hipLaunchKernelGGL(k_transpose_x, dim3(64, 8, 16), dim3(256), 0, stream, x, xT);
    hipLaunchKernelGGL(k_proj, dim3(32, 3, 16), dim3(256), 0, stream, xT, Wb, thn, phip, gp);
    hipLaunchKernelGGL(k_attn, dim3(32, 16), dim3(256), 0, stream, thn, phip, gp, oin);
    hipLaunchKernelGGL(k_oproj, dim3(32, 4, 16), dim3(256), 0, stream, oin, oWb, x, gamma, out);
}

// Round 10
// 192.154 us; speedup vs baseline: 1.0444x; 1.0006x over previous
//
#include <hip/hip_runtime.h>

// Problem constants
#define B_   16
#define C_   512
#define HW_  4096
#define M_   1024   // pooled positions (HW/4)
#define TPAD 136    // LDS epilogue row pad (ushorts): 272 B = 16B-aligned rows

typedef __attribute__((ext_vector_type(8))) short bf16x8;   // 8 bf16 = 4 VGPR
typedef __attribute__((ext_vector_type(4))) float f32x4;

static __device__ __forceinline__ unsigned short f2bf(float f) {
    union { float f; unsigned u; } v; v.f = f;
    unsigned r = v.u + 0x7fffu + ((v.u >> 16) & 1u);  // RNE
    return (unsigned short)(r >> 16);
}
static __device__ __forceinline__ float bf2f(unsigned short h) {
    union { unsigned u; float f; } v; v.u = ((unsigned)h) << 16;
    return v.f;
}
static __device__ __forceinline__ void gload_lds16(const void* g, void* l) {
    __builtin_amdgcn_global_load_lds(
        (const __attribute__((address_space(1))) unsigned int*)g,
        (__attribute__((address_space(3))) unsigned int*)l, 16, 0, 0);
}
// pack 2 f32 -> 2 bf16 in one u32 (RNE), single VALU op
static __device__ __forceinline__ unsigned cvt_pk(float lo, float hi) {
    unsigned r;
    asm("v_cvt_pk_bf16_f32 %0, %1, %2" : "=v"(r) : "v"(lo), "v"(hi));
    return r;
}

// ---------------------------------------------------------------------------
// K00: convert weights to bf16.
// Wb rows: [0,64) theta_w, [64,128) phi_w, [128,384) g_w. oWb = o_w [512][256].
__global__ __launch_bounds__(256) void k_weights(
    const float* __restrict__ thw, const float* __restrict__ phw,
    const float* __restrict__ gw,  const float* __restrict__ ow,
    unsigned short* __restrict__ Wb, unsigned short* __restrict__ oWb) {
    int i = blockIdx.x * 256 + threadIdx.x;
    if (i < 32768)        Wb[i] = f2bf(thw[i]);
    else if (i < 65536)   Wb[i] = f2bf(phw[i - 32768]);
    else if (i < 196608)  Wb[i] = f2bf(gw[i - 65536]);
    else if (i < 327680)  oWb[i - 196608] = f2bf(ow[i - 196608]);
}

// ---------------------------------------------------------------------------
// K1: ONE-PASS native-x projection GEMM (no transpose kernel, no xT buffer).
// Each block: ALL 384 proj rows x 128 hw-cols, batch b -> x read ONCE (128 MB).
// x fp32 staged global->LDS via global_load_lds w16 (deep issue queue saturates
// HBM delivery), double-buffered. B-fragments: 8x ds_read_b32 (stride 512 B,
// 2-way via ((c>>3)&1)<<4 hw-XOR pre-applied on the GLOBAL source) +
// 4x v_cvt_pk_bf16_f32. A (weights, L2-hot) direct global->VGPR, issued BEFORE
// the next-tile stage so the vmcnt wait on A is counted, not a drain.
// 512 thr / 8 waves (4 rg x 2 cg; wave tile 96x64; acc[6][4]).
// FUSED epilogue (r7-proven): 3 chunk passes -> theta_n / phi pool / g pool.
__global__ __launch_bounds__(512, 2) void k_proj(
    const float* __restrict__ x, const unsigned short* __restrict__ Wb,
    unsigned short* __restrict__ theta_n, unsigned short* __restrict__ phi_p,
    unsigned short* __restrict__ g_p) {
    __shared__ float xlds[2][64 * 128];           // 2 x 32 KB fp32 x-tile
    __shared__ unsigned short smem[128 * TPAD];   // 34,816 B epilogue restage

    int b = blockIdx.y, bx = blockIdx.x;
    int hw0 = bx * 128;
    int tid = threadIdx.x, w = tid >> 6, lane = tid & 63;
    int l15 = lane & 15, q = lane >> 4;
    int rg = w >> 1, cg = w & 1;                 // wave: 96-row group, 64-col group

    const float* xb = x + (size_t)b * C_ * HW_ + hw0;

    // stage k-step ks_ into xlds[buf_]: 2048 x 16B units, 4 issues/thread.
    // lds[c*128 + h'] = x[c][h' ^ swz(c)], swz(c) = ((c>>3)&1)<<4 (floats)
#define STAGEX(ks_, buf_)                                                      \
    _Pragma("unroll")                                                          \
    for (int i = 0; i < 4; i++) {                                              \
        int u = i * 512 + tid;                                                 \
        int c = u >> 5, chunk = u & 31;                                        \
        int swz = ((c >> 3) & 1) << 4;                                         \
        gload_lds16(xb + (size_t)((ks_) * 64 + c) * HW_ + ((chunk * 4) ^ swz), \
                    &xlds[buf_][(i * 512 + w * 64) * 4]);                      \
    }

    STAGEX(0, 0);
    __syncthreads();   // prologue drain

    f32x4 acc[6][4] = {};
    for (int ks = 0; ks < 8; ks++) {
        int cur = ks & 1;
        // ---- A fragments FIRST (12 global loads; older than stage in FIFO)
        bf16x8 af[2][6];
#pragma unroll
        for (int kk = 0; kk < 2; kk++)
#pragma unroll
            for (int mi = 0; mi < 6; mi++) {
                int row = rg * 96 + mi * 16 + l15;
                af[kk][mi] = *(const bf16x8*)(Wb + (size_t)row * 512 + ks * 64 + kk * 32 + q * 8);
            }
        // ---- issue next k-step's stage (drains at end-of-iter barrier)
        if (ks < 7) { STAGEX(ks + 1, cur ^ 1); }
        // ---- compute: B-frags from fp32 LDS (scalar b32 + cvt_pk), MFMA
#pragma unroll
        for (int kk = 0; kk < 2; kk++) {
#pragma unroll
            for (int ni = 0; ni < 4; ni++) {
                int colsw = (cg * 64 + ni * 16 + l15) ^ ((q & 1) << 4);
                const float* base = &xlds[cur][(kk * 32 + q * 8) * 128 + colsw];
                float f0 = base[0],   f1 = base[128], f2 = base[256], f3 = base[384];
                float f4 = base[512], f5 = base[640], f6 = base[768], f7 = base[896];
                bf16x8 bfr;
                unsigned* bw = (unsigned*)&bfr;
                bw[0] = cvt_pk(f0, f1); bw[1] = cvt_pk(f2, f3);
                bw[2] = cvt_pk(f4, f5); bw[3] = cvt_pk(f6, f7);
#pragma unroll
                for (int mi = 0; mi < 6; mi++)
                    acc[mi][ni] = __builtin_amdgcn_mfma_f32_16x16x32_bf16(
                        af[kk][mi], bfr, acc[mi][ni], 0, 0, 0);
            }
        }
        __syncthreads();  // drains stage(ks+1); guards xlds[cur] reuse
    }
#undef STAGEX

    // ---- epilogue: 3 chunk passes over smem[col(hw_l)][row(ch in chunk)], pad 136
    for (int t = 0; t < 3; t++) {
        __syncthreads();
#pragma unroll
        for (int mi = 0; mi < 6; mi++) {
            int grow = rg * 96 + mi * 16;
            if ((grow >> 7) == t) {
#pragma unroll
                for (int ni = 0; ni < 4; ni++) {
                    int col = cg * 64 + ni * 16 + l15;
                    int row = (grow & 127) + q * 4;
                    ushort4 u;
                    u.x = f2bf(acc[mi][ni][0]); u.y = f2bf(acc[mi][ni][1]);
                    u.z = f2bf(acc[mi][ni][2]); u.w = f2bf(acc[mi][ni][3]);
                    *reinterpret_cast<ushort4*>(&smem[col * TPAD + row]) = u;
                }
            }
        }
        __syncthreads();

        if (t == 0) {
            // theta rows 0..63 -> theta_n[b][hw][k]: thread = 1 hw x 16 k (32 B)
            int hw_l = tid >> 2, kh = (tid & 3) * 16;
            const unsigned short* srcp = &smem[hw_l * TPAD + kh];
            unsigned short* dstp = theta_n + ((size_t)b * HW_ + hw0 + hw_l) * 64 + kh;
            *reinterpret_cast<uint4*>(dstp)     = *reinterpret_cast<const uint4*>(srcp);
            *reinterpret_cast<uint4*>(dstp + 8) = *reinterpret_cast<const uint4*>(srcp + 8);
            // phi rows 64..127 -> pool -> phi_p[b][m][64]: thread = 4 m x 1 pc
            int pc = tid & 63, mg = tid >> 6;
#pragma unroll
            for (int j = 0; j < 4; j++) {
                int m_l = mg * 4 + j, w_ = m_l * 2;
                float v0 = bf2f(smem[(w_)      * TPAD + 64 + pc]);
                float v1 = bf2f(smem[(w_ + 1)  * TPAD + 64 + pc]);
                float v2 = bf2f(smem[(64 + w_) * TPAD + 64 + pc]);
                float v3 = bf2f(smem[(65 + w_) * TPAD + 64 + pc]);
                float v = fmaxf(fmaxf(v0, v1), fmaxf(v2, v3));
                phi_p[((size_t)b * M_ + bx * 32 + m_l) * 64 + pc] = f2bf(v);
            }
        } else {
            // g chunk (t-1): rows = g channels (t-1)*128 + lr; thread = 1 gc x 8 m
            int lr = tid & 127, mq = tid >> 7;
            int gc = (t - 1) * 128 + lr;
            unsigned short* dst = g_p + ((size_t)b * 256 + gc) * M_ + bx * 32 + mq * 8;
            unsigned short tmp[8];
#pragma unroll
            for (int i = 0; i < 8; i++) {
                int w_ = (mq * 8 + i) * 2;
                float v0 = bf2f(smem[(w_)      * TPAD + lr]);
                float v1 = bf2f(smem[(w_ + 1)  * TPAD + lr]);
                float v2 = bf2f(smem[(64 + w_) * TPAD + lr]);
                float v3 = bf2f(smem[(65 + w_) * TPAD + lr]);
                tmp[i] = f2bf(fmaxf(fmaxf(v0, v1), fmaxf(v2, v3)));
            }
            *reinterpret_cast<ushort4*>(dst)     = *reinterpret_cast<const ushort4*>(&tmp[0]);
            *reinterpret_cast<ushort4*>(dst + 4) = *reinterpret_cast<const ushort4*>(&tmp[4]);
        }
    }
}

// ---------------------------------------------------------------------------
// K3: fused attention -> o_in [B][4096][256] bf16.
// Block = 256 threads (4 waves), 32 query rows PER WAVE (128/block), batch b.
// attn is LDS-port-bound; 32 rows/wave makes each g-fragment read feed 2 MFMA.
// Per m-chunk (64 cols): stage phi[64][64] + g[256][64] via global_load_lds
// w16 (chunk-XOR pre-swizzled on the GLOBAL side), then S = theta@phi,
// P = exp(S) (no max-sub; logits bounded), O += P@g^T. Softmax denominator
// via compile-time ones-fragment (acc[t][16]); g rows 256+ never exist.
__global__ __launch_bounds__(256, 2) void k_attn(
    const unsigned short* __restrict__ theta_n, const unsigned short* __restrict__ phi_p,
    const unsigned short* __restrict__ g_p, unsigned short* __restrict__ o_in) {
    __shared__ unsigned short phi_s[64 * 64];      //  8 KB, row=m (64 elems, 8 chunks)
    __shared__ unsigned short g_s[256 * 64];       // 32 KB, row=c
    __shared__ unsigned short p_lds[4][32][68];    // 17 KB, per-wave P [32n][64m], pad 68

    int b = blockIdx.y, n0 = blockIdx.x * 128;
    int tid = threadIdx.x, w = tid >> 6, lane = tid & 63;
    int l15 = lane & 15, q = lane >> 4;
    int nw = n0 + w * 32;

    // theta A-fragments (held all kernel): 2 row-groups x 2 k-frags
    const unsigned short* th = theta_n + ((size_t)b * HW_ + nw + l15) * 64 + q * 8;
    bf16x8 a[2][2];
    a[0][0] = *(const bf16x8*)(th);            a[0][1] = *(const bf16x8*)(th + 32);
    a[1][0] = *(const bf16x8*)(th + 16 * 64);  a[1][1] = *(const bf16x8*)(th + 16 * 64 + 32);

    const unsigned short* phib = phi_p + (size_t)b * M_ * 64;
    const unsigned short* gb   = g_p   + (size_t)b * 256 * M_;

    // constant denominator B-fragment: column n=l15 -> 1.0 iff l15==0, all k
    bf16x8 ones;
    {
        short v = (l15 == 0) ? (short)0x3F80 : (short)0;
#pragma unroll
        for (int i = 0; i < 8; i++) ones[i] = v;
    }

    int sw = l15 & 7;  // read-side XOR (row & 7 == l15 & 7 for fragment rows)

    f32x4 acc[2][17] = {};  // [row-group][16 c-frags + denom]
    for (int mc = 0; mc < 16; mc++) {
        int m0 = mc * 64;
        __syncthreads();   // prior chunk's LDS reads complete before overwrite
        // ---- stage phi chunk: 512 x 16B units, 2 issues/thread
#pragma unroll
        for (int i = 0; i < 2; i++) {
            int u = i * 256 + tid;
            int row = u >> 3, ch = (lane & 7) ^ (row & 7);
            gload_lds16(phib + (size_t)(m0 + row) * 64 + ch * 8,
                        &phi_s[(i * 256 + w * 64) * 8]);
        }
        // ---- stage g chunk: 2048 x 16B units, 8 issues/thread
#pragma unroll
        for (int i = 0; i < 8; i++) {
            int u = i * 256 + tid;
            int row = u >> 3, ch = (lane & 7) ^ (row & 7);
            gload_lds16(gb + (size_t)row * M_ + m0 + ch * 8,
                        &g_s[(i * 256 + w * 64) * 8]);
        }
        __syncthreads();   // vmcnt(0) drain + barrier

        // ---- S phase: S[32n][64m]; phi reads amortize over 2 row-groups
#pragma unroll
        for (int f = 0; f < 4; f++) {
            const unsigned short* pr = &phi_s[(f * 16 + l15) * 64];
            bf16x8 b0 = *(const bf16x8*)(pr + (q ^ sw) * 8);
            bf16x8 b1 = *(const bf16x8*)(pr + ((q + 4) ^ sw) * 8);
#pragma unroll
            for (int t = 0; t < 2; t++) {
                f32x4 s = {};
                s = __builtin_amdgcn_mfma_f32_16x16x32_bf16(a[t][0], b0, s, 0, 0, 0);
                s = __builtin_amdgcn_mfma_f32_16x16x32_bf16(a[t][1], b1, s, 0, 0, 0);
#pragma unroll
                for (int j = 0; j < 4; j++)
                    p_lds[w][t * 16 + q * 4 + j][f * 16 + l15] = f2bf(__expf(s[j]));
            }
        }
        // ---- P A-fragments from LDS (same-wave dep; compiler inserts lgkmcnt)
        bf16x8 p[2][2];
#pragma unroll
        for (int t = 0; t < 2; t++) {
            p[t][0] = *(const bf16x8*)&p_lds[w][t * 16 + l15][q * 8];
            p[t][1] = *(const bf16x8*)&p_lds[w][t * 16 + l15][32 + q * 8];
        }
        // ---- O phase: each g-fragment read feeds BOTH row-groups (2x amortize)
#pragma unroll
        for (int cf = 0; cf < 16; cf++) {
            const unsigned short* gr = &g_s[(cf * 16 + l15) * 64];
            bf16x8 g0 = *(const bf16x8*)(gr + (q ^ sw) * 8);
            bf16x8 g1 = *(const bf16x8*)(gr + ((q + 4) ^ sw) * 8);
#pragma unroll
            for (int t = 0; t < 2; t++) {
                acc[t][cf] = __builtin_amdgcn_mfma_f32_16x16x32_bf16(p[t][0], g0, acc[t][cf], 0, 0, 0);
                acc[t][cf] = __builtin_amdgcn_mfma_f32_16x16x32_bf16(p[t][1], g1, acc[t][cf], 0, 0, 0);
            }
        }
#pragma unroll
        for (int t = 0; t < 2; t++) {
            acc[t][16] = __builtin_amdgcn_mfma_f32_16x16x32_bf16(p[t][0], ones, acc[t][16], 0, 0, 0);
            acc[t][16] = __builtin_amdgcn_mfma_f32_16x16x32_bf16(p[t][1], ones, acc[t][16], 0, 0, 0);
        }
    }

    // ---- epilogue: divide by denominator (frag 16, col 0 => lanes l15==0)
#pragma unroll
    for (int t = 0; t < 2; t++) {
        float dinv[4];
#pragma unroll
        for (int j = 0; j < 4; j++) {
            float d = __shfl(acc[t][16][j], (lane & 48), 64);
            dinv[j] = 1.0f / d;
        }
#pragma unroll
        for (int cf = 0; cf < 16; cf++)
#pragma unroll
            for (int j = 0; j < 4; j++)
                o_in[((size_t)b * HW_ + nw + t * 16 + q * 4 + j) * 256 + cf * 16 + l15] =
                    f2bf(acc[t][cf][j] * dinv[j]);
    }
}

// ---------------------------------------------------------------------------
// K4: output projection + residual: out[b][cout][hw] = gamma * (o_in @ oW^T) + x
// m97 mainloop + LDS-restaged epilogue: tile -> smem[row][col] (pad 136),
// then 32-lane groups write 512 B contiguous float4 rows (x reads coalesced).
__global__ __launch_bounds__(256, 4) void k_oproj(
    const unsigned short* __restrict__ o_in, const unsigned short* __restrict__ oWb,
    const float* __restrict__ x, const float* __restrict__ gamma_p,
    float* __restrict__ out) {
    __shared__ unsigned short smem[128 * TPAD];   // 34,816 B; aliases As|Bs
    unsigned short* As = smem;
    unsigned short* Bs = smem + 8192;

    int b = blockIdx.z, mt = blockIdx.y, hw0 = blockIdx.x * 128;
    int tid = threadIdx.x, w = tid >> 6, lane = tid & 63;
    int l15 = lane & 15, q = lane >> 4;
    int wr = w >> 1, wc = w & 1;

    const unsigned short* Ab = oWb + (size_t)(mt * 128) * 256;
    const unsigned short* Bb = o_in + ((size_t)b * HW_ + hw0) * 256;
    int trow = tid >> 3, tch = tid & 7;

    f32x4 acc[4][4] = {};
    for (int ks = 0; ks < 4; ks++) {
        int k0 = ks * 64;
        if (ks) __syncthreads();
#pragma unroll
        for (int i = 0; i < 4; i++) {
            int row = i * 32 + trow;
            int ch = tch ^ (row & 7);
            gload_lds16(Ab + (size_t)row * 256 + k0 + ch * 8, &As[(i * 256 + w * 64) * 8]);
        }
#pragma unroll
        for (int i = 0; i < 4; i++) {
            int row = i * 32 + trow;
            int ch = tch ^ (row & 7);
            gload_lds16(Bb + (size_t)row * 256 + k0 + ch * 8, &Bs[(i * 256 + w * 64) * 8]);
        }
        __syncthreads();
#pragma unroll
        for (int kk = 0; kk < 2; kk++) {
            bf16x8 af[4], bfr[4];
#pragma unroll
            for (int mi = 0; mi < 4; mi++) {
                int row = wr * 64 + mi * 16 + l15;
                int ch = (kk * 4 + q) ^ (row & 7);
                af[mi] = *(const bf16x8*)&As[row * 64 + ch * 8];
            }
#pragma unroll
            for (int ni = 0; ni < 4; ni++) {
                int row = wc * 64 + ni * 16 + l15;
                int ch = (kk * 4 + q) ^ (row & 7);
                bfr[ni] = *(const bf16x8*)&Bs[row * 64 + ch * 8];
            }
#pragma unroll
            for (int mi = 0; mi < 4; mi++)
#pragma unroll
                for (int ni = 0; ni < 4; ni++)
                    acc[mi][ni] = __builtin_amdgcn_mfma_f32_16x16x32_bf16(
                        af[mi], bfr[ni], acc[mi][ni], 0, 0, 0);
        }
    }

    // ---- epilogue: restage row-major smem[row(cout_l)][col(hw_l)], pad 136
    __syncthreads();
#pragma unroll
    for (int mi = 0; mi < 4; mi++)
#pragma unroll
        for (int ni = 0; ni < 4; ni++) {
            int col = wc * 64 + ni * 16 + l15;
            int rb = wr * 64 + mi * 16 + q * 4;
#pragma unroll
            for (int j = 0; j < 4; j++)
                smem[(rb + j) * TPAD + col] = f2bf(acc[mi][ni][j]);
        }
    __syncthreads();

    float gam = *gamma_p;
    int sub = tid >> 5, p32 = tid & 31;
#pragma unroll
    for (int p = 0; p < 16; p++) {
        int row = p * 8 + sub;
        ushort4 v = *reinterpret_cast<const ushort4*>(&smem[row * TPAD + p32 * 4]);
        size_t idx = ((size_t)b * C_ + mt * 128 + row) * HW_ + hw0 + p32 * 4;
        float4 xv = *reinterpret_cast<const float4*>(x + idx);
        float4 o;
        o.x = gam * bf2f(v.x) + xv.x;
        o.y = gam * bf2f(v.y) + xv.y;
        o.z = gam * bf2f(v.z) + xv.z;
        o.w = gam * bf2f(v.w) + xv.w;
        *reinterpret_cast<float4*>(out + idx) = o;
    }
}

// ---------------------------------------------------------------------------
extern "C" void kernel_launch(void* const* d_in, const int* in_sizes, int n_in,
                              void* d_out, int out_size, void* d_ws, size_t ws_size,
                              hipStream_t stream) {
    const float* x     = (const float*)d_in[0];
    const float* thw   = (const float*)d_in[1];
    const float* phw   = (const float*)d_in[2];
    const float* gw    = (const float*)d_in[3];
    const float* ow    = (const float*)d_in[4];
    const float* gamma = (const float*)d_in[5];
    float* out = (float*)d_out;

    char* ws = (char*)d_ws;
    // workspace layout (bytes), all 256-aligned; total 53,084,160
    unsigned short* Wb   = (unsigned short*)(ws + 0);          //     393,216
    unsigned short* oWb  = (unsigned short*)(ws + 393216);     //     262,144
    unsigned short* oin  = (unsigned short*)(ws + 655360);     //  33,554,432
    unsigned short* thn  = (unsigned short*)(ws + 34209792);   //   8,388,608
    unsigned short* phip = (unsigned short*)(ws + 42598400);   //   2,097,152
    unsigned short* gp   = (unsigned short*)(ws + 44695552);   //   8,388,608 (256 rows/b)

    hipLaunchKernelGGL(k_weights, dim3(1280), dim3(256), 0, stream, thw, phw, gw, ow, Wb, oWb);
    hipLaunchKernelGGL(k_proj, dim3(32, 16), dim3(512), 0, stream, x, Wb, thn, phip, gp);
    hipLaunchKernelGGL(k_attn, dim3(32, 16), dim3(256), 0, stream, thn, phip, gp, oin);
    hipLaunchKernelGGL(k_oproj, dim3(32, 4, 16), dim3(256), 0, stream, oin, oWb, x, gamma, out);
}

// Round 11
// 191.877 us; speedup vs baseline: 1.0459x; 1.0014x over previous
//
#include <hip/hip_runtime.h>

// Problem constants
#define B_   16
#define C_   512
#define HW_  4096
#define M_   1024   // pooled positions (HW/4)
#define TPAD 136    // LDS epilogue row pad (ushorts): 272 B = 16B-aligned rows

typedef __attribute__((ext_vector_type(8))) short bf16x8;   // 8 bf16 = 4 VGPR
typedef __attribute__((ext_vector_type(4))) float f32x4;

static __device__ __forceinline__ unsigned short f2bf(float f) {
    union { float f; unsigned u; } v; v.f = f;
    unsigned r = v.u + 0x7fffu + ((v.u >> 16) & 1u);  // RNE
    return (unsigned short)(r >> 16);
}
static __device__ __forceinline__ float bf2f(unsigned short h) {
    union { unsigned u; float f; } v; v.u = ((unsigned)h) << 16;
    return v.f;
}
static __device__ __forceinline__ void gload_lds16(const void* g, void* l) {
    __builtin_amdgcn_global_load_lds(
        (const __attribute__((address_space(1))) unsigned int*)g,
        (__attribute__((address_space(3))) unsigned int*)l, 16, 0, 0);
}
// pack 2 f32 -> 2 bf16 in one u32 (RNE), single VALU op
static __device__ __forceinline__ unsigned cvt_pk(float lo, float hi) {
    unsigned r;
    asm("v_cvt_pk_bf16_f32 %0, %1, %2" : "=v"(r) : "v"(lo), "v"(hi));
    return r;
}

// ---------------------------------------------------------------------------
// K00: convert weights to bf16.
// Wb rows: [0,64) theta_w, [64,128) phi_w, [128,384) g_w. oWb = o_w [512][256].
__global__ __launch_bounds__(256) void k_weights(
    const float* __restrict__ thw, const float* __restrict__ phw,
    const float* __restrict__ gw,  const float* __restrict__ ow,
    unsigned short* __restrict__ Wb, unsigned short* __restrict__ oWb) {
    int i = blockIdx.x * 256 + threadIdx.x;
    if (i < 32768)        Wb[i] = f2bf(thw[i]);
    else if (i < 65536)   Wb[i] = f2bf(phw[i - 32768]);
    else if (i < 196608)  Wb[i] = f2bf(gw[i - 65536]);
    else if (i < 327680)  oWb[i - 196608] = f2bf(ow[i - 196608]);
}

// ---------------------------------------------------------------------------
// K1: ONE-PASS native-x projection GEMM (no transpose kernel, no xT buffer).
// Each block: ALL 384 proj rows x 128 hw-cols, batch b -> x read ONCE (128 MB).
// x fp32 staged global->LDS via global_load_lds w16, double-buffered.
// B-fragments: 8x ds_read_b32 (stride 512 B, 2-way via ((c>>3)&1)<<4 hw-XOR
// pre-applied on the GLOBAL source) + 4x v_cvt_pk_bf16_f32. A (weights,
// L2-hot) direct global->VGPR. 512 thr / 8 waves (4 rg x 2 cg; tile 96x64).
// r11 fix: epilogue restage buffer ALIASED onto xlds (dead after k-loop,
// barrier-separated) -> LDS 100,352 -> 65,536 B -> 2 blocks/CU, so the other
// block's compute covers this block's per-k-step stage drain (m114 overlap).
// FUSED epilogue (r7-proven): 3 chunk passes -> theta_n / phi pool / g pool.
__global__ __launch_bounds__(512, 2) void k_proj(
    const float* __restrict__ x, const unsigned short* __restrict__ Wb,
    unsigned short* __restrict__ theta_n, unsigned short* __restrict__ phi_p,
    unsigned short* __restrict__ g_p) {
    __shared__ float xlds[2][64 * 128];           // 2 x 32 KB fp32 x-tile (65,536 B total)
    unsigned short* smem = (unsigned short*)&xlds[0][0];  // epilogue alias (34,816 B)

    int b = blockIdx.y, bx = blockIdx.x;
    int hw0 = bx * 128;
    int tid = threadIdx.x, w = tid >> 6, lane = tid & 63;
    int l15 = lane & 15, q = lane >> 4;
    int rg = w >> 1, cg = w & 1;                 // wave: 96-row group, 64-col group

    const float* xb = x + (size_t)b * C_ * HW_ + hw0;

    // stage k-step ks_ into xlds[buf_]: 2048 x 16B units, 4 issues/thread.
    // lds[c*128 + h'] = x[c][h' ^ swz(c)], swz(c) = ((c>>3)&1)<<4 (floats)
#define STAGEX(ks_, buf_)                                                      \
    _Pragma("unroll")                                                          \
    for (int i = 0; i < 4; i++) {                                              \
        int u = i * 512 + tid;                                                 \
        int c = u >> 5, chunk = u & 31;                                        \
        int swz = ((c >> 3) & 1) << 4;                                         \
        gload_lds16(xb + (size_t)((ks_) * 64 + c) * HW_ + ((chunk * 4) ^ swz), \
                    &xlds[buf_][(i * 512 + w * 64) * 4]);                      \
    }

    STAGEX(0, 0);
    __syncthreads();   // prologue drain

    f32x4 acc[6][4] = {};
    for (int ks = 0; ks < 8; ks++) {
        int cur = ks & 1;
        // ---- A fragments FIRST (12 global loads; older than stage in FIFO)
        bf16x8 af[2][6];
#pragma unroll
        for (int kk = 0; kk < 2; kk++)
#pragma unroll
            for (int mi = 0; mi < 6; mi++) {
                int row = rg * 96 + mi * 16 + l15;
                af[kk][mi] = *(const bf16x8*)(Wb + (size_t)row * 512 + ks * 64 + kk * 32 + q * 8);
            }
        // ---- issue next k-step's stage (drains at end-of-iter barrier)
        if (ks < 7) { STAGEX(ks + 1, cur ^ 1); }
        // ---- compute: B-frags from fp32 LDS (scalar b32 + cvt_pk), MFMA
#pragma unroll
        for (int kk = 0; kk < 2; kk++) {
#pragma unroll
            for (int ni = 0; ni < 4; ni++) {
                int colsw = (cg * 64 + ni * 16 + l15) ^ ((q & 1) << 4);
                const float* base = &xlds[cur][(kk * 32 + q * 8) * 128 + colsw];
                float f0 = base[0],   f1 = base[128], f2 = base[256], f3 = base[384];
                float f4 = base[512], f5 = base[640], f6 = base[768], f7 = base[896];
                bf16x8 bfr;
                unsigned* bw = (unsigned*)&bfr;
                bw[0] = cvt_pk(f0, f1); bw[1] = cvt_pk(f2, f3);
                bw[2] = cvt_pk(f4, f5); bw[3] = cvt_pk(f6, f7);
#pragma unroll
                for (int mi = 0; mi < 6; mi++)
                    acc[mi][ni] = __builtin_amdgcn_mfma_f32_16x16x32_bf16(
                        af[kk][mi], bfr, acc[mi][ni], 0, 0, 0);
            }
        }
        __syncthreads();  // drains stage(ks+1); guards xlds[cur] reuse
    }
#undef STAGEX

    // ---- epilogue: 3 chunk passes over smem[col(hw_l)][row(ch in chunk)], pad 136
    // (smem aliases xlds; all xlds reads completed before first barrier below)
    for (int t = 0; t < 3; t++) {
        __syncthreads();
#pragma unroll
        for (int mi = 0; mi < 6; mi++) {
            int grow = rg * 96 + mi * 16;
            if ((grow >> 7) == t) {
#pragma unroll
                for (int ni = 0; ni < 4; ni++) {
                    int col = cg * 64 + ni * 16 + l15;
                    int row = (grow & 127) + q * 4;
                    ushort4 u;
                    u.x = f2bf(acc[mi][ni][0]); u.y = f2bf(acc[mi][ni][1]);
                    u.z = f2bf(acc[mi][ni][2]); u.w = f2bf(acc[mi][ni][3]);
                    *reinterpret_cast<ushort4*>(&smem[col * TPAD + row]) = u;
                }
            }
        }
        __syncthreads();

        if (t == 0) {
            // theta rows 0..63 -> theta_n[b][hw][k]: thread = 1 hw x 16 k (32 B)
            int hw_l = tid >> 2, kh = (tid & 3) * 16;
            const unsigned short* srcp = &smem[hw_l * TPAD + kh];
            unsigned short* dstp = theta_n + ((size_t)b * HW_ + hw0 + hw_l) * 64 + kh;
            *reinterpret_cast<uint4*>(dstp)     = *reinterpret_cast<const uint4*>(srcp);
            *reinterpret_cast<uint4*>(dstp + 8) = *reinterpret_cast<const uint4*>(srcp + 8);
            // phi rows 64..127 -> pool -> phi_p[b][m][64]: thread = 4 m x 1 pc
            int pc = tid & 63, mg = tid >> 6;
#pragma unroll
            for (int j = 0; j < 4; j++) {
                int m_l = mg * 4 + j, w_ = m_l * 2;
                float v0 = bf2f(smem[(w_)      * TPAD + 64 + pc]);
                float v1 = bf2f(smem[(w_ + 1)  * TPAD + 64 + pc]);
                float v2 = bf2f(smem[(64 + w_) * TPAD + 64 + pc]);
                float v3 = bf2f(smem[(65 + w_) * TPAD + 64 + pc]);
                float v = fmaxf(fmaxf(v0, v1), fmaxf(v2, v3));
                phi_p[((size_t)b * M_ + bx * 32 + m_l) * 64 + pc] = f2bf(v);
            }
        } else {
            // g chunk (t-1): rows = g channels (t-1)*128 + lr; thread = 1 gc x 8 m
            int lr = tid & 127, mq = tid >> 7;
            int gc = (t - 1) * 128 + lr;
            unsigned short* dst = g_p + ((size_t)b * 256 + gc) * M_ + bx * 32 + mq * 8;
            unsigned short tmp[8];
#pragma unroll
            for (int i = 0; i < 8; i++) {
                int w_ = (mq * 8 + i) * 2;
                float v0 = bf2f(smem[(w_)      * TPAD + lr]);
                float v1 = bf2f(smem[(w_ + 1)  * TPAD + lr]);
                float v2 = bf2f(smem[(64 + w_) * TPAD + lr]);
                float v3 = bf2f(smem[(65 + w_) * TPAD + lr]);
                tmp[i] = f2bf(fmaxf(fmaxf(v0, v1), fmaxf(v2, v3)));
            }
            *reinterpret_cast<ushort4*>(dst)     = *reinterpret_cast<const ushort4*>(&tmp[0]);
            *reinterpret_cast<ushort4*>(dst + 4) = *reinterpret_cast<const ushort4*>(&tmp[4]);
        }
    }
}

// ---------------------------------------------------------------------------
// K3: fused attention -> o_in [B][4096][256] bf16.
// Block = 256 threads (4 waves), 32 query rows PER WAVE (128/block), batch b.
// attn is LDS-port-bound; 32 rows/wave makes each g-fragment read feed 2 MFMA.
// Per m-chunk (64 cols): stage phi[64][64] + g[256][64] via global_load_lds
// w16 (chunk-XOR pre-swizzled on the GLOBAL side), then S = theta@phi,
// P = exp(S) (no max-sub; logits bounded), O += P@g^T. Softmax denominator
// via compile-time ones-fragment (acc[t][16]); g rows 256+ never exist.
__global__ __launch_bounds__(256, 2) void k_attn(
    const unsigned short* __restrict__ theta_n, const unsigned short* __restrict__ phi_p,
    const unsigned short* __restrict__ g_p, unsigned short* __restrict__ o_in) {
    __shared__ unsigned short phi_s[64 * 64];      //  8 KB, row=m (64 elems, 8 chunks)
    __shared__ unsigned short g_s[256 * 64];       // 32 KB, row=c
    __shared__ unsigned short p_lds[4][32][68];    // 17 KB, per-wave P [32n][64m], pad 68

    int b = blockIdx.y, n0 = blockIdx.x * 128;
    int tid = threadIdx.x, w = tid >> 6, lane = tid & 63;
    int l15 = lane & 15, q = lane >> 4;
    int nw = n0 + w * 32;

    // theta A-fragments (held all kernel): 2 row-groups x 2 k-frags
    const unsigned short* th = theta_n + ((size_t)b * HW_ + nw + l15) * 64 + q * 8;
    bf16x8 a[2][2];
    a[0][0] = *(const bf16x8*)(th);            a[0][1] = *(const bf16x8*)(th + 32);
    a[1][0] = *(const bf16x8*)(th + 16 * 64);  a[1][1] = *(const bf16x8*)(th + 16 * 64 + 32);

    const unsigned short* phib = phi_p + (size_t)b * M_ * 64;
    const unsigned short* gb   = g_p   + (size_t)b * 256 * M_;

    // constant denominator B-fragment: column n=l15 -> 1.0 iff l15==0, all k
    bf16x8 ones;
    {
        short v = (l15 == 0) ? (short)0x3F80 : (short)0;
#pragma unroll
        for (int i = 0; i < 8; i++) ones[i] = v;
    }

    int sw = l15 & 7;  // read-side XOR (row & 7 == l15 & 7 for fragment rows)

    f32x4 acc[2][17] = {};  // [row-group][16 c-frags + denom]
    for (int mc = 0; mc < 16; mc++) {
        int m0 = mc * 64;
        __syncthreads();   // prior chunk's LDS reads complete before overwrite
        // ---- stage phi chunk: 512 x 16B units, 2 issues/thread
#pragma unroll
        for (int i = 0; i < 2; i++) {
            int u = i * 256 + tid;
            int row = u >> 3, ch = (lane & 7) ^ (row & 7);
            gload_lds16(phib + (size_t)(m0 + row) * 64 + ch * 8,
                        &phi_s[(i * 256 + w * 64) * 8]);
        }
        // ---- stage g chunk: 2048 x 16B units, 8 issues/thread
#pragma unroll
        for (int i = 0; i < 8; i++) {
            int u = i * 256 + tid;
            int row = u >> 3, ch = (lane & 7) ^ (row & 7);
            gload_lds16(gb + (size_t)row * M_ + m0 + ch * 8,
                        &g_s[(i * 256 + w * 64) * 8]);
        }
        __syncthreads();   // vmcnt(0) drain + barrier

        // ---- S phase: S[32n][64m]; phi reads amortize over 2 row-groups
#pragma unroll
        for (int f = 0; f < 4; f++) {
            const unsigned short* pr = &phi_s[(f * 16 + l15) * 64];
            bf16x8 b0 = *(const bf16x8*)(pr + (q ^ sw) * 8);
            bf16x8 b1 = *(const bf16x8*)(pr + ((q + 4) ^ sw) * 8);
#pragma unroll
            for (int t = 0; t < 2; t++) {
                f32x4 s = {};
                s = __builtin_amdgcn_mfma_f32_16x16x32_bf16(a[t][0], b0, s, 0, 0, 0);
                s = __builtin_amdgcn_mfma_f32_16x16x32_bf16(a[t][1], b1, s, 0, 0, 0);
#pragma unroll
                for (int j = 0; j < 4; j++)
                    p_lds[w][t * 16 + q * 4 + j][f * 16 + l15] = f2bf(__expf(s[j]));
            }
        }
        // ---- P A-fragments from LDS (same-wave dep; compiler inserts lgkmcnt)
        bf16x8 p[2][2];
#pragma unroll
        for (int t = 0; t < 2; t++) {
            p[t][0] = *(const bf16x8*)&p_lds[w][t * 16 + l15][q * 8];
            p[t][1] = *(const bf16x8*)&p_lds[w][t * 16 + l15][32 + q * 8];
        }
        // ---- O phase: each g-fragment read feeds BOTH row-groups (2x amortize)
#pragma unroll
        for (int cf = 0; cf < 16; cf++) {
            const unsigned short* gr = &g_s[(cf * 16 + l15) * 64];
            bf16x8 g0 = *(const bf16x8*)(gr + (q ^ sw) * 8);
            bf16x8 g1 = *(const bf16x8*)(gr + ((q + 4) ^ sw) * 8);
#pragma unroll
            for (int t = 0; t < 2; t++) {
                acc[t][cf] = __builtin_amdgcn_mfma_f32_16x16x32_bf16(p[t][0], g0, acc[t][cf], 0, 0, 0);
                acc[t][cf] = __builtin_amdgcn_mfma_f32_16x16x32_bf16(p[t][1], g1, acc[t][cf], 0, 0, 0);
            }
        }
#pragma unroll
        for (int t = 0; t < 2; t++) {
            acc[t][16] = __builtin_amdgcn_mfma_f32_16x16x32_bf16(p[t][0], ones, acc[t][16], 0, 0, 0);
            acc[t][16] = __builtin_amdgcn_mfma_f32_16x16x32_bf16(p[t][1], ones, acc[t][16], 0, 0, 0);
        }
    }

    // ---- epilogue: divide by denominator (frag 16, col 0 => lanes l15==0)
#pragma unroll
    for (int t = 0; t < 2; t++) {
        float dinv[4];
#pragma unroll
        for (int j = 0; j < 4; j++) {
            float d = __shfl(acc[t][16][j], (lane & 48), 64);
            dinv[j] = 1.0f / d;
        }
#pragma unroll
        for (int cf = 0; cf < 16; cf++)
#pragma unroll
            for (int j = 0; j < 4; j++)
                o_in[((size_t)b * HW_ + nw + t * 16 + q * 4 + j) * 256 + cf * 16 + l15] =
                    f2bf(acc[t][cf][j] * dinv[j]);
    }
}

// ---------------------------------------------------------------------------
// K4: output projection + residual: out[b][cout][hw] = gamma * (o_in @ oW^T) + x
// m97 mainloop + LDS-restaged epilogue: tile -> smem[row][col] (pad 136),
// then 32-lane groups write 512 B contiguous float4 rows (x reads coalesced).
__global__ __launch_bounds__(256, 4) void k_oproj(
    const unsigned short* __restrict__ o_in, const unsigned short* __restrict__ oWb,
    const float* __restrict__ x, const float* __restrict__ gamma_p,
    float* __restrict__ out) {
    __shared__ unsigned short smem[128 * TPAD];   // 34,816 B; aliases As|Bs
    unsigned short* As = smem;
    unsigned short* Bs = smem + 8192;

    int b = blockIdx.z, mt = blockIdx.y, hw0 = blockIdx.x * 128;
    int tid = threadIdx.x, w = tid >> 6, lane = tid & 63;
    int l15 = lane & 15, q = lane >> 4;
    int wr = w >> 1, wc = w & 1;

    const unsigned short* Ab = oWb + (size_t)(mt * 128) * 256;
    const unsigned short* Bb = o_in + ((size_t)b * HW_ + hw0) * 256;
    int trow = tid >> 3, tch = tid & 7;

    f32x4 acc[4][4] = {};
    for (int ks = 0; ks < 4; ks++) {
        int k0 = ks * 64;
        if (ks) __syncthreads();
#pragma unroll
        for (int i = 0; i < 4; i++) {
            int row = i * 32 + trow;
            int ch = tch ^ (row & 7);
            gload_lds16(Ab + (size_t)row * 256 + k0 + ch * 8, &As[(i * 256 + w * 64) * 8]);
        }
#pragma unroll
        for (int i = 0; i < 4; i++) {
            int row = i * 32 + trow;
            int ch = tch ^ (row & 7);
            gload_lds16(Bb + (size_t)row * 256 + k0 + ch * 8, &Bs[(i * 256 + w * 64) * 8]);
        }
        __syncthreads();
#pragma unroll
        for (int kk = 0; kk < 2; kk++) {
            bf16x8 af[4], bfr[4];
#pragma unroll
            for (int mi = 0; mi < 4; mi++) {
                int row = wr * 64 + mi * 16 + l15;
                int ch = (kk * 4 + q) ^ (row & 7);
                af[mi] = *(const bf16x8*)&As[row * 64 + ch * 8];
            }
#pragma unroll
            for (int ni = 0; ni < 4; ni++) {
                int row = wc * 64 + ni * 16 + l15;
                int ch = (kk * 4 + q) ^ (row & 7);
                bfr[ni] = *(const bf16x8*)&Bs[row * 64 + ch * 8];
            }
#pragma unroll
            for (int mi = 0; mi < 4; mi++)
#pragma unroll
                for (int ni = 0; ni < 4; ni++)
                    acc[mi][ni] = __builtin_amdgcn_mfma_f32_16x16x32_bf16(
                        af[mi], bfr[ni], acc[mi][ni], 0, 0, 0);
        }
    }

    // ---- epilogue: restage row-major smem[row(cout_l)][col(hw_l)], pad 136
    __syncthreads();
#pragma unroll
    for (int mi = 0; mi < 4; mi++)
#pragma unroll
        for (int ni = 0; ni < 4; ni++) {
            int col = wc * 64 + ni * 16 + l15;
            int rb = wr * 64 + mi * 16 + q * 4;
#pragma unroll
            for (int j = 0; j < 4; j++)
                smem[(rb + j) * TPAD + col] = f2bf(acc[mi][ni][j]);
        }
    __syncthreads();

    float gam = *gamma_p;
    int sub = tid >> 5, p32 = tid & 31;
#pragma unroll
    for (int p = 0; p < 16; p++) {
        int row = p * 8 + sub;
        ushort4 v = *reinterpret_cast<const ushort4*>(&smem[row * TPAD + p32 * 4]);
        size_t idx = ((size_t)b * C_ + mt * 128 + row) * HW_ + hw0 + p32 * 4;
        float4 xv = *reinterpret_cast<const float4*>(x + idx);
        float4 o;
        o.x = gam * bf2f(v.x) + xv.x;
        o.y = gam * bf2f(v.y) + xv.y;
        o.z = gam * bf2f(v.z) + xv.z;
        o.w = gam * bf2f(v.w) + xv.w;
        *reinterpret_cast<float4*>(out + idx) = o;
    }
}

// ---------------------------------------------------------------------------
extern "C" void kernel_launch(void* const* d_in, const int* in_sizes, int n_in,
                              void* d_out, int out_size, void* d_ws, size_t ws_size,
                              hipStream_t stream) {
    const float* x     = (const float*)d_in[0];
    const float* thw   = (const float*)d_in[1];
    const float* phw   = (const float*)d_in[2];
    const float* gw    = (const float*)d_in[3];
    const float* ow    = (const float*)d_in[4];
    const float* gamma = (const float*)d_in[5];
    float* out = (float*)d_out;

    char* ws = (char*)d_ws;
    // workspace layout (bytes), all 256-aligned; total 53,084,160
    unsigned short* Wb   = (unsigned short*)(ws + 0);          //     393,216
    unsigned short* oWb  = (unsigned short*)(ws + 393216);     //     262,144
    unsigned short* oin  = (unsigned short*)(ws + 655360);     //  33,554,432
    unsigned short* thn  = (unsigned short*)(ws + 34209792);   //   8,388,608
    unsigned short* phip = (unsigned short*)(ws + 42598400);   //   2,097,152
    unsigned short* gp   = (unsigned short*)(ws + 44695552);   //   8,388,608 (256 rows/b)

    hipLaunchKernelGGL(k_weights, dim3(1280), dim3(256), 0, stream, thw, phw, gw, ow, Wb, oWb);
    hipLaunchKernelGGL(k_proj, dim3(32, 16), dim3(512), 0, stream, x, Wb, thn, phip, gp);
    hipLaunchKernelGGL(k_attn, dim3(32, 16), dim3(256), 0, stream, thn, phip, gp, oin);
    hipLaunchKernelGGL(k_oproj, dim3(32, 4, 16), dim3(256), 0, stream, oin, oWb, x, gamma, out);
}